// Round 10
// baseline (193.763 us; speedup 1.0000x reference)
//
#include <hip/hip_runtime.h>
#include <hip/hip_bf16.h>
#include <stdint.h>

namespace {

constexpr int Bb = 2;
constexpr int Hh = 16;
constexpr int Ss = 2048;
constexpr int Dd = 64;
constexpr int KT = 64;                   // keys per stored tile
constexpr int NT = Ss / KT;              // 32 stored key tiles
constexpr int TILE_BYTES = KT * Dd * 2;  // 8192 B per bf16 tile
constexpr int BH_BYTES = NT * TILE_BYTES;
constexpr size_t KPRE_BYTES = (size_t)Bb * Hh * Ss * Dd * 2;  // 8 MB
constexpr size_t VPRE_OFF = KPRE_BYTES;
constexpr size_t MASK_OFF = 2 * KPRE_BYTES;
constexpr int NIT = 16;                   // 128-key iterations
constexpr int IT_BYTES = 2 * TILE_BYTES;  // 16 KB per tensor per iter

typedef __bf16 bf16x8 __attribute__((ext_vector_type(8)));
typedef float floatx4 __attribute__((ext_vector_type(4)));

// ---------------- preprocess4: ZERO LDS (validated R4) ----------------
__global__ __launch_bounds__(256) void preprocess4(
    const float* __restrict__ K, const float* __restrict__ V,
    const int* __restrict__ mask, uint8_t* __restrict__ ws)
{
  const int tid = threadIdx.x;
  const int kt = blockIdx.x;
  const int bh = blockIdx.y;

  if (blockIdx.z == 0) {
    const int c = tid & 7;
#pragma unroll
    for (int half = 0; half < 2; ++half) {
      const int row = (tid >> 3) + half * 32;
      const float4* src = (const float4*)(K + ((size_t)bh * 2048 + kt * 64 + row) * 64 + c * 8);
      const float4 a = src[0], b2 = src[1];
      bf16x8 pk;
      pk[0] = (__bf16)a.x;  pk[1] = (__bf16)a.y;  pk[2] = (__bf16)a.z;  pk[3] = (__bf16)a.w;
      pk[4] = (__bf16)b2.x; pk[5] = (__bf16)b2.y; pk[6] = (__bf16)b2.z; pk[7] = (__bf16)b2.w;
      uint8_t* dst = ws + (size_t)bh * BH_BYTES + kt * TILE_BYTES + row * 128 + ((c ^ (row & 7)) << 4);
      *(bf16x8*)dst = pk;
    }
    if (bh == 0 && kt < 16) {
      const int i = kt * 256 + tid;
      const int bb = i >> 11, key = i & 2047;
      const unsigned long long bal = __ballot(mask[bb * 2048 + key] != 0);
      if ((key & 63) == 0)
        ((unsigned long long*)(ws + MASK_OFF))[bb * NT + (key >> 6)] = bal;
    }
    return;
  }

  // ---- V: direct transposed gather (no LDS) ----
  const int d2  = tid & 31;
  const int c16 = tid >> 5;
  const int s2 = c16 & 1, q = c16 >> 1;
  const int k0 = 32 * s2 + 4 * q;
  const float* vbase = V + ((size_t)bh * 2048 + kt * 64) * 64;
  float2 col[8];
#pragma unroll
  for (int j = 0; j < 4; ++j) {
    col[j]     = *(const float2*)(vbase + (size_t)(k0 + j) * 64 + 2 * d2);
    col[4 + j] = *(const float2*)(vbase + (size_t)(k0 + 16 + j) * 64 + 2 * d2);
  }
#pragma unroll
  for (int h = 0; h < 2; ++h) {
    const int d = 2 * d2 + h;
    bf16x8 pv;
#pragma unroll
    for (int j = 0; j < 4; ++j) {
      pv[j]     = (__bf16)(h ? col[j].y     : col[j].x);
      pv[4 + j] = (__bf16)(h ? col[4 + j].y : col[4 + j].x);
    }
    uint8_t* dst = ws + VPRE_OFF + (size_t)bh * BH_BYTES + kt * TILE_BYTES + d * 128 + ((c16 ^ (d & 7)) << 4);
    *(bf16x8*)dst = pv;
  }
}

// -10000 * log2(e): reference's masked_fill value, in exp2 domain.
#define NEGM (-14426.950408889634f)
#define MFMA16 __builtin_amdgcn_mfma_f32_16x16x32_bf16

// ---------------- fused attention, T14 async-STAGE split ----------------
// Geometry identical to fused7 (best measured 54.7us: 128-key iters, 4-wave
// blocks, 64 KiB LDS, dual q-streams, 2-pair register pipeline, setprio).
// CHANGE (m214 T14, their +17%): replace global_load_lds staging with
// reg-staging. g2lds forces `s_waitcnt vmcnt(0)` at every __syncthreads -
// every wave waits for the slowest wave's global loads 16x per kernel. Now:
// issue global_load->regs for tile it+2 EARLY (right after this iter's
// ds_writes), ds_write tile it+1 -> back buffer right AFTER the barrier.
// The barrier drains only lgkmcnt (ds_write ~40cyc); global latency sits in
// flight under a full iteration of compute (~600cyc). Two alternating named
// reg sets (ka/va, kb/vb) - all indices compile-time (rule #20 safe).
__global__ __launch_bounds__(256, 2) void attn_fused13(
    const float* __restrict__ Q, const uint8_t* __restrict__ ws,
    float* __restrict__ Out)
{
  const int tid  = threadIdx.x;
  const int wave = tid >> 6;
  const int lane = tid & 63;
  const int ln   = lane & 15;
  const int quad = lane >> 4;

  const int bh   = blockIdx.x;  // 0..31
  const int qblk = blockIdx.y;  // 0..15
  const int b    = bh >> 4;

  const float* Qb = Q + (size_t)bh * Ss * Dd;
  float*       Ob = Out + (size_t)bh * Ss * Dd;
  const uint8_t* Kpre = ws + (size_t)bh * BH_BYTES;
  const uint8_t* Vpre = ws + VPRE_OFF + (size_t)bh * BH_BYTES;
  const unsigned long long* Mbits = (const unsigned long long*)(ws + MASK_OFF) + b * NT;

  __shared__ __align__(16) __bf16 Klds[2][128 * Dd];   // 2 x 16 KB
  __shared__ __align__(16) __bf16 Vlds[2][128 * Dd];   // 2 x 16 KB

  const int q0A = qblk * 128 + wave * 32;
  const int q0B = q0A + 16;

  // Q B-frags, pre-scaled by 1/8*log2(e). B[k=quad*8+j][n=ln] = Qs[q][d].
  const float QS = 0.125f * 1.44269504088896340736f;
  bf16x8 aqA0, aqA1, aqB0, aqB1;
  {
    const float* qpA = Qb + (size_t)(q0A + ln) * Dd + quad * 8;
    const float* qpB = Qb + (size_t)(q0B + ln) * Dd + quad * 8;
#pragma unroll
    for (int j = 0; j < 8; ++j) {
      aqA0[j] = (__bf16)(qpA[j] * QS);
      aqA1[j] = (__bf16)(qpA[32 + j] * QS);
      aqB0[j] = (__bf16)(qpB[j] * QS);
      aqB1[j] = (__bf16)(qpB[32 + j] * QS);
    }
  }

  floatx4 oA[4], oB[4];    // O^T C-layout: d = nd*16+quad*4+r, q = ln
  floatx4 laccA = (floatx4){0.f, 0.f, 0.f, 0.f};
  floatx4 laccB = (floatx4){0.f, 0.f, 0.f, 0.f};
#pragma unroll
  for (int nd = 0; nd < 4; ++nd) {
    oA[nd] = (floatx4){0.f, 0.f, 0.f, 0.f};
    oB[nd] = (floatx4){0.f, 0.f, 0.f, 0.f};
  }

  const int swz0 = (quad ^ (ln & 7)) << 4;
  const int swz1 = ((quad + 4) ^ (ln & 7)) << 4;
  const int soff = wave * 4096 + lane * 16;  // 16 KB per tensor per iter

  // ---- reg staging helpers (all indices compile-time) ----
  float4 ka[4], va[4], kb[4], vb[4];
  auto loadRegs = [&](int it, float4* k, float4* v) {
#pragma unroll
    for (int i = 0; i < 4; ++i) {
      k[i] = *(const float4*)(Kpre + (size_t)it * IT_BYTES + soff + i * 1024);
      v[i] = *(const float4*)(Vpre + (size_t)it * IT_BYTES + soff + i * 1024);
    }
  };
  auto writeLds = [&](int buf, const float4* k, const float4* v) {
#pragma unroll
    for (int i = 0; i < 4; ++i) {
      *(float4*)((uint8_t*)Klds[buf] + soff + i * 1024) = k[i];
      *(float4*)((uint8_t*)Vlds[buf] + soff + i * 1024) = v[i];
    }
  };

// compute on buffer CUR with mask words MB0/MB1 (fused7 body, unchanged)
#define COMPUTE(CUR, MB0, MB1)                                                \
  {                                                                           \
    const unsigned long long mb0 = (MB0);                                     \
    const unsigned long long mb1 = (MB1);                                     \
    const uint8_t* Kb = (const uint8_t*)Klds[(CUR)];                          \
    const uint8_t* Vb = (const uint8_t*)Vlds[(CUR)];                          \
    auto loadK = [&](int sub, bf16x8& b0, bf16x8& b1) {                       \
      const uint8_t* krow =                                                   \
          Kb + (sub >> 2) * 8192 + ((sub & 3) * 16 + ln) * 128;               \
      b0 = *(const bf16x8*)(krow + swz0);                                     \
      b1 = *(const bf16x8*)(krow + swz1);                                     \
    };                                                                        \
    auto loadV = [&](int p_, bf16x8* w) {                                     \
      const int T = p_ >> 1, s2 = p_ & 1;                                     \
      _Pragma("unroll")                                                       \
      for (int nd = 0; nd < 4; ++nd) {                                        \
        const uint8_t* vrow = Vb + T * 8192 + (nd * 16 + ln) * 128;           \
        w[nd] = *(const bf16x8*)(vrow + (((quad * 2 + s2) ^ (ln & 7)) << 4)); \
      }                                                                       \
    };                                                                        \
    __builtin_amdgcn_s_setprio(1);                                            \
    bf16x8 kf0[2][2], kf1[2][2];                                              \
    bf16x8 vf[2][4];                                                          \
    loadK(0, kf0[0][0], kf1[0][0]);                                           \
    loadK(1, kf0[0][1], kf1[0][1]);                                           \
    loadV(0, vf[0]);                                                          \
    _Pragma("unroll")                                                         \
    for (int p = 0; p < 4; ++p) {                                             \
      const int cb = p & 1, nb = cb ^ 1;                                      \
      if (p < 3) {                                                            \
        loadK(2 * p + 2, kf0[nb][0], kf1[nb][0]);                             \
        loadK(2 * p + 3, kf0[nb][1], kf1[nb][1]);                             \
        loadV(p + 1, vf[nb]);                                                 \
      }                                                                       \
      const unsigned long long mbx = (p & 2) ? mb1 : mb0;                     \
      const uint32_t bits0 =                                                  \
          (uint32_t)(mbx >> ((((2 * p) & 3) * 16) + quad * 4));               \
      const uint32_t bits1 =                                                  \
          (uint32_t)(mbx >> ((((2 * p + 1) & 3) * 16) + quad * 4));           \
      floatx4 sA0, sA1, sB0, sB1;                                             \
      _Pragma("unroll")                                                       \
      for (int r = 0; r < 4; ++r) {                                           \
        const float b0v = ((bits0 >> r) & 1) ? NEGM : 0.f;                    \
        const float b1v = ((bits1 >> r) & 1) ? NEGM : 0.f;                    \
        sA0[r] = b0v; sB0[r] = b0v;                                           \
        sA1[r] = b1v; sB1[r] = b1v;                                           \
      }                                                                       \
      sA0 = MFMA16(kf0[cb][0], aqA0, sA0, 0, 0, 0);                           \
      sA0 = MFMA16(kf1[cb][0], aqA1, sA0, 0, 0, 0);                           \
      sB0 = MFMA16(kf0[cb][0], aqB0, sB0, 0, 0, 0);                           \
      sB0 = MFMA16(kf1[cb][0], aqB1, sB0, 0, 0, 0);                           \
      sA1 = MFMA16(kf0[cb][1], aqA0, sA1, 0, 0, 0);                           \
      sA1 = MFMA16(kf1[cb][1], aqA1, sA1, 0, 0, 0);                           \
      sB1 = MFMA16(kf0[cb][1], aqB0, sB1, 0, 0, 0);                           \
      sB1 = MFMA16(kf1[cb][1], aqB1, sB1, 0, 0, 0);                           \
      bf16x8 bpA, bpB;                                                        \
      _Pragma("unroll")                                                       \
      for (int r = 0; r < 4; ++r) {                                           \
        const float pA0 = __builtin_amdgcn_exp2f(sA0[r]);                     \
        const float pA1 = __builtin_amdgcn_exp2f(sA1[r]);                     \
        const float pB0 = __builtin_amdgcn_exp2f(sB0[r]);                     \
        const float pB1 = __builtin_amdgcn_exp2f(sB1[r]);                     \
        laccA[r] += pA0 + pA1;                                                \
        laccB[r] += pB0 + pB1;                                                \
        bpA[r] = (__bf16)pA0; bpA[4 + r] = (__bf16)pA1;                       \
        bpB[r] = (__bf16)pB0; bpB[4 + r] = (__bf16)pB1;                       \
      }                                                                       \
      _Pragma("unroll")                                                       \
      for (int nd = 0; nd < 4; ++nd) {                                        \
        oA[nd] = MFMA16(vf[cb][nd], bpA, oA[nd], 0, 0, 0);                    \
        oB[nd] = MFMA16(vf[cb][nd], bpB, oB[nd], 0, 0, 0);                    \
      }                                                                       \
    }                                                                         \
    __builtin_amdgcn_s_setprio(0);                                            \
  }

// ITER: barrier; ds_write tile IT+1 (in W-set); issue loads tile IT+2 (L-set);
// compute tile IT. Barrier closes prev reads of buf[(IT+1)&1] AND makes prev
// iter's ds_writes (buf[IT&1]) visible (lgkm drained - cheap, no vmcnt(0)).
#define ITER(IT, WK, WV, LK, LV)                                              \
  {                                                                           \
    __syncthreads();                                                          \
    if ((IT) + 1 < NIT) writeLds(((IT) + 1) & 1, WK, WV);                     \
    if ((IT) + 2 < NIT) loadRegs((IT) + 2, LK, LV);                           \
    COMPUTE((IT) & 1, Mbits[2 * (IT)], Mbits[2 * (IT) + 1]);                  \
  }

  // prologue: tile0 -> regs -> buf0 (vmcnt wait auto); tile1 -> ka in flight
  loadRegs(0, kb, vb);
  writeLds(0, kb, vb);
  loadRegs(1, ka, va);

  for (int it2 = 0; it2 < NIT; it2 += 2) {
    ITER(it2,     ka, va, kb, vb);
    ITER(it2 + 1, kb, vb, ka, va);
  }

#undef ITER
#undef COMPUTE

  // ---- epilogue: reduce l across quads, normalize, store ----
  float lA = (laccA[0] + laccA[1]) + (laccA[2] + laccA[3]);
  float lB = (laccB[0] + laccB[1]) + (laccB[2] + laccB[3]);
  lA += __shfl_xor(lA, 16); lA += __shfl_xor(lA, 32);
  lB += __shfl_xor(lB, 16); lB += __shfl_xor(lB, 32);
  const float iA = 1.0f / lA, iB = 1.0f / lB;
#pragma unroll
  for (int nd = 0; nd < 4; ++nd) {
    float4 wv;
    wv.x = oA[nd][0] * iA; wv.y = oA[nd][1] * iA;
    wv.z = oA[nd][2] * iA; wv.w = oA[nd][3] * iA;
    *(float4*)(Ob + (size_t)(q0A + ln) * Dd + nd * 16 + quad * 4) = wv;
    wv.x = oB[nd][0] * iB; wv.y = oB[nd][1] * iB;
    wv.z = oB[nd][2] * iB; wv.w = oB[nd][3] * iB;
    *(float4*)(Ob + (size_t)(q0B + ln) * Dd + nd * 16 + quad * 4) = wv;
  }
}

}  // namespace

extern "C" void kernel_launch(void* const* d_in, const int* in_sizes, int n_in,
                              void* d_out, int out_size, void* d_ws, size_t ws_size,
                              hipStream_t stream) {
  const float* Q   = (const float*)d_in[0];
  const float* K   = (const float*)d_in[1];
  const float* V   = (const float*)d_in[2];
  const int*  mask = (const int*)d_in[3];
  float* Out = (float*)d_out;

  preprocess4<<<dim3(32, 32, 2), 256, 0, stream>>>(K, V, mask, (uint8_t*)d_ws);
  attn_fused13<<<dim3(Bb * Hh, Ss / 128), 256, 0, stream>>>(Q, (const uint8_t*)d_ws, Out);
  (void)ws_size; (void)in_sizes; (void)n_in; (void)out_size;
}

// Round 11
// 177.319 us; speedup vs baseline: 1.0927x; 1.0927x over previous
//
#include <hip/hip_runtime.h>
#include <hip/hip_bf16.h>
#include <stdint.h>

namespace {

constexpr int Bb = 2;
constexpr int Hh = 16;
constexpr int Ss = 2048;
constexpr int Dd = 64;
constexpr int KT = 64;                   // keys per stored tile
constexpr int NT = Ss / KT;              // 32 stored key tiles
constexpr int TILE_BYTES = KT * Dd * 2;  // 8192 B per bf16 tile
constexpr int BH_BYTES = NT * TILE_BYTES;
constexpr size_t KPRE_BYTES = (size_t)Bb * Hh * Ss * Dd * 2;  // 8 MB
constexpr size_t VPRE_OFF = KPRE_BYTES;
constexpr size_t MASK_OFF = 2 * KPRE_BYTES;

typedef __bf16 bf16x8 __attribute__((ext_vector_type(8)));
typedef float floatx4 __attribute__((ext_vector_type(4)));

// ---------------- preprocess4: ZERO LDS (validated R4) ----------------
__global__ __launch_bounds__(256) void preprocess4(
    const float* __restrict__ K, const float* __restrict__ V,
    const int* __restrict__ mask, uint8_t* __restrict__ ws)
{
  const int tid = threadIdx.x;
  const int kt = blockIdx.x;
  const int bh = blockIdx.y;

  if (blockIdx.z == 0) {
    const int c = tid & 7;
#pragma unroll
    for (int half = 0; half < 2; ++half) {
      const int row = (tid >> 3) + half * 32;
      const float4* src = (const float4*)(K + ((size_t)bh * 2048 + kt * 64 + row) * 64 + c * 8);
      const float4 a = src[0], b2 = src[1];
      bf16x8 pk;
      pk[0] = (__bf16)a.x;  pk[1] = (__bf16)a.y;  pk[2] = (__bf16)a.z;  pk[3] = (__bf16)a.w;
      pk[4] = (__bf16)b2.x; pk[5] = (__bf16)b2.y; pk[6] = (__bf16)b2.z; pk[7] = (__bf16)b2.w;
      uint8_t* dst = ws + (size_t)bh * BH_BYTES + kt * TILE_BYTES + row * 128 + ((c ^ (row & 7)) << 4);
      *(bf16x8*)dst = pk;
    }
    if (bh == 0 && kt < 16) {
      const int i = kt * 256 + tid;
      const int bb = i >> 11, key = i & 2047;
      const unsigned long long bal = __ballot(mask[bb * 2048 + key] != 0);
      if ((key & 63) == 0)
        ((unsigned long long*)(ws + MASK_OFF))[bb * NT + (key >> 6)] = bal;
    }
    return;
  }

  // ---- V: direct transposed gather (no LDS) ----
  const int d2  = tid & 31;
  const int c16 = tid >> 5;
  const int s2 = c16 & 1, q = c16 >> 1;
  const int k0 = 32 * s2 + 4 * q;
  const float* vbase = V + ((size_t)bh * 2048 + kt * 64) * 64;
  float2 col[8];
#pragma unroll
  for (int j = 0; j < 4; ++j) {
    col[j]     = *(const float2*)(vbase + (size_t)(k0 + j) * 64 + 2 * d2);
    col[4 + j] = *(const float2*)(vbase + (size_t)(k0 + 16 + j) * 64 + 2 * d2);
  }
#pragma unroll
  for (int h = 0; h < 2; ++h) {
    const int d = 2 * d2 + h;
    bf16x8 pv;
#pragma unroll
    for (int j = 0; j < 4; ++j) {
      pv[j]     = (__bf16)(h ? col[j].y     : col[j].x);
      pv[4 + j] = (__bf16)(h ? col[4 + j].y : col[4 + j].x);
    }
    uint8_t* dst = ws + VPRE_OFF + (size_t)bh * BH_BYTES + kt * TILE_BYTES + d * 128 + ((c16 ^ (d & 7)) << 4);
    *(bf16x8*)dst = pv;
  }
}

// -10000 * log2(e): reference's masked_fill value, in exp2 domain.
#define NEGM (-14426.950408889634f)
#define MFMA16 __builtin_amdgcn_mfma_f32_16x16x32_bf16

// ---------------- fused attention, T14 @ KVBLK=64 (16-reg staging) -------
// R10 lesson: T14 at 128-key granularity needed 64 staging VGPRs -> spill
// (WRITE_SIZE 195MB). The m214 kernel that measured +17% staged 8KB tiles:
// 2 float4/tensor/thread = 16 VGPRs. THIS round: R5's KVBLK=64 geometry
// (32 KiB LDS, 80 VGPR natural, 56.7us) + reg-staging split: issue
// global_load->regs for tile it+2 early, ds_write tile it+1 right after
// the barrier. Barrier drains only lgkm (cheap ds_writes) instead of
// vmcnt(0) global tails; loads get a full iteration (~600cyc) to land.
// Two alternating named reg sets (rule #20 safe). VGPR ~112 <= 2-wave cap.
__global__ __launch_bounds__(256, 2) void attn_fused14(
    const float* __restrict__ Q, const uint8_t* __restrict__ ws,
    float* __restrict__ Out)
{
  const int tid  = threadIdx.x;
  const int wave = tid >> 6;
  const int lane = tid & 63;
  const int ln   = lane & 15;
  const int quad = lane >> 4;

  const int bh   = blockIdx.x;  // 0..31
  const int qblk = blockIdx.y;  // 0..15
  const int b    = bh >> 4;

  const float* Qb = Q + (size_t)bh * Ss * Dd;
  float*       Ob = Out + (size_t)bh * Ss * Dd;
  const uint8_t* Kpre = ws + (size_t)bh * BH_BYTES;
  const uint8_t* Vpre = ws + VPRE_OFF + (size_t)bh * BH_BYTES;
  const unsigned long long* Mbits = (const unsigned long long*)(ws + MASK_OFF) + b * NT;

  __shared__ __align__(16) __bf16 Klds[2][64 * Dd];   // 2 x 8 KB
  __shared__ __align__(16) __bf16 Vlds[2][64 * Dd];   // 2 x 8 KB

  const int q0A = qblk * 128 + wave * 32;
  const int q0B = q0A + 16;

  // Q B-frags, pre-scaled by 1/8*log2(e). B[k=quad*8+j][n=ln] = Qs[q][d].
  const float QS = 0.125f * 1.44269504088896340736f;
  bf16x8 aqA0, aqA1, aqB0, aqB1;
  {
    const float* qpA = Qb + (size_t)(q0A + ln) * Dd + quad * 8;
    const float* qpB = Qb + (size_t)(q0B + ln) * Dd + quad * 8;
#pragma unroll
    for (int j = 0; j < 8; ++j) {
      aqA0[j] = (__bf16)(qpA[j] * QS);
      aqA1[j] = (__bf16)(qpA[32 + j] * QS);
      aqB0[j] = (__bf16)(qpB[j] * QS);
      aqB1[j] = (__bf16)(qpB[32 + j] * QS);
    }
  }

  floatx4 oA[4], oB[4];    // O^T C-layout: d = nd*16+quad*4+r, q = ln
  floatx4 laccA = (floatx4){0.f, 0.f, 0.f, 0.f};
  floatx4 laccB = (floatx4){0.f, 0.f, 0.f, 0.f};
#pragma unroll
  for (int nd = 0; nd < 4; ++nd) {
    oA[nd] = (floatx4){0.f, 0.f, 0.f, 0.f};
    oB[nd] = (floatx4){0.f, 0.f, 0.f, 0.f};
  }

  const int swz0 = (quad ^ (ln & 7)) << 4;
  const int swz1 = ((quad + 4) ^ (ln & 7)) << 4;
  const int soff = wave * 1024 + lane * 16;  // 4 KB per round, 2 rounds/tile

  // ---- reg staging: 2 float4 per tensor per thread (16 VGPR total/set) --
  float4 ka[2], va[2], kb[2], vb[2];
  auto loadRegs = [&](int it, float4* k, float4* v) {
    k[0] = *(const float4*)(Kpre + (size_t)it * TILE_BYTES + soff);
    k[1] = *(const float4*)(Kpre + (size_t)it * TILE_BYTES + soff + 4096);
    v[0] = *(const float4*)(Vpre + (size_t)it * TILE_BYTES + soff);
    v[1] = *(const float4*)(Vpre + (size_t)it * TILE_BYTES + soff + 4096);
  };
  auto writeLds = [&](int buf, const float4* k, const float4* v) {
    *(float4*)((uint8_t*)Klds[buf] + soff)        = k[0];
    *(float4*)((uint8_t*)Klds[buf] + soff + 4096) = k[1];
    *(float4*)((uint8_t*)Vlds[buf] + soff)        = v[0];
    *(float4*)((uint8_t*)Vlds[buf] + soff + 4096) = v[1];
  };

// compute on buffer CUR with mask word MB (R5 body, unchanged)
#define COMPUTE(CUR, MB)                                                      \
  {                                                                           \
    const unsigned long long mb = (MB);                                       \
    const uint8_t* Kb = (const uint8_t*)Klds[(CUR)];                          \
    const uint8_t* Vb = (const uint8_t*)Vlds[(CUR)];                          \
    auto loadK = [&](int sub, bf16x8& b0, bf16x8& b1) {                       \
      const uint8_t* krow = Kb + (sub * 16 + ln) * 128;                       \
      b0 = *(const bf16x8*)(krow + swz0);                                     \
      b1 = *(const bf16x8*)(krow + swz1);                                     \
    };                                                                        \
    auto loadV = [&](int s2_, bf16x8* w) {                                    \
      _Pragma("unroll")                                                       \
      for (int nd = 0; nd < 4; ++nd) {                                        \
        const uint8_t* vrow = Vb + (nd * 16 + ln) * 128;                      \
        w[nd] = *(const bf16x8*)(vrow + (((quad * 2 + s2_) ^ (ln & 7)) << 4));\
      }                                                                       \
    };                                                                        \
    __builtin_amdgcn_s_setprio(1);                                            \
    bf16x8 kf0[2][2], kf1[2][2];                                              \
    bf16x8 vf[2][4];                                                          \
    loadK(0, kf0[0][0], kf1[0][0]);                                           \
    loadK(1, kf0[0][1], kf1[0][1]);                                           \
    loadV(0, vf[0]);                                                          \
    _Pragma("unroll")                                                         \
    for (int p = 0; p < 2; ++p) {                                             \
      if (p == 0) {                                                           \
        loadK(2, kf0[1][0], kf1[1][0]);                                       \
        loadK(3, kf0[1][1], kf1[1][1]);                                       \
        loadV(1, vf[1]);                                                      \
      }                                                                       \
      const uint32_t bits0 = (uint32_t)(mb >> ((2 * p) * 16 + quad * 4));     \
      const uint32_t bits1 = (uint32_t)(mb >> ((2 * p + 1) * 16 + quad * 4)); \
      floatx4 sA0, sA1, sB0, sB1;                                             \
      _Pragma("unroll")                                                       \
      for (int r = 0; r < 4; ++r) {                                           \
        const float b0v = ((bits0 >> r) & 1) ? NEGM : 0.f;                    \
        const float b1v = ((bits1 >> r) & 1) ? NEGM : 0.f;                    \
        sA0[r] = b0v; sB0[r] = b0v;                                           \
        sA1[r] = b1v; sB1[r] = b1v;                                           \
      }                                                                       \
      sA0 = MFMA16(kf0[p][0], aqA0, sA0, 0, 0, 0);                            \
      sA0 = MFMA16(kf1[p][0], aqA1, sA0, 0, 0, 0);                            \
      sB0 = MFMA16(kf0[p][0], aqB0, sB0, 0, 0, 0);                            \
      sB0 = MFMA16(kf1[p][0], aqB1, sB0, 0, 0, 0);                            \
      sA1 = MFMA16(kf0[p][1], aqA0, sA1, 0, 0, 0);                            \
      sA1 = MFMA16(kf1[p][1], aqA1, sA1, 0, 0, 0);                            \
      sB1 = MFMA16(kf0[p][1], aqB0, sB1, 0, 0, 0);                            \
      sB1 = MFMA16(kf1[p][1], aqB1, sB1, 0, 0, 0);                            \
      bf16x8 bpA, bpB;                                                        \
      _Pragma("unroll")                                                       \
      for (int r = 0; r < 4; ++r) {                                           \
        const float pA0 = __builtin_amdgcn_exp2f(sA0[r]);                     \
        const float pA1 = __builtin_amdgcn_exp2f(sA1[r]);                     \
        const float pB0 = __builtin_amdgcn_exp2f(sB0[r]);                     \
        const float pB1 = __builtin_amdgcn_exp2f(sB1[r]);                     \
        laccA[r] += pA0 + pA1;                                                \
        laccB[r] += pB0 + pB1;                                                \
        bpA[r] = (__bf16)pA0; bpA[4 + r] = (__bf16)pA1;                       \
        bpB[r] = (__bf16)pB0; bpB[4 + r] = (__bf16)pB1;                       \
      }                                                                       \
      _Pragma("unroll")                                                       \
      for (int nd = 0; nd < 4; ++nd) {                                        \
        oA[nd] = MFMA16(vf[p][nd], bpA, oA[nd], 0, 0, 0);                     \
        oB[nd] = MFMA16(vf[p][nd], bpB, oB[nd], 0, 0, 0);                     \
      }                                                                       \
    }                                                                         \
    __builtin_amdgcn_s_setprio(0);                                            \
  }

// ITER: barrier; ds_write tile IT+1 (W-set); issue loads tile IT+2 (L-set);
// compute tile IT. Barrier closes prev reads of buf[(IT+1)&1] and publishes
// prev ds_writes of buf[IT&1]; only lgkm drains at it (no vmcnt(0) tail).
#define ITER(IT, WK, WV, LK, LV)                                              \
  {                                                                           \
    __syncthreads();                                                          \
    if ((IT) + 1 < NT) writeLds(((IT) + 1) & 1, WK, WV);                      \
    if ((IT) + 2 < NT) loadRegs((IT) + 2, LK, LV);                            \
    COMPUTE((IT) & 1, Mbits[(IT)]);                                           \
  }

  // prologue: tile0 -> regs -> buf0; tile1 -> ka/va (in flight).
  loadRegs(0, kb, vb);
  writeLds(0, kb, vb);
  loadRegs(1, ka, va);

  for (int it2 = 0; it2 < NT; it2 += 2) {
    ITER(it2,     ka, va, kb, vb);
    ITER(it2 + 1, kb, vb, ka, va);
  }

#undef ITER
#undef COMPUTE

  // ---- epilogue: reduce l across quads, normalize, store ----
  float lA = (laccA[0] + laccA[1]) + (laccA[2] + laccA[3]);
  float lB = (laccB[0] + laccB[1]) + (laccB[2] + laccB[3]);
  lA += __shfl_xor(lA, 16); lA += __shfl_xor(lA, 32);
  lB += __shfl_xor(lB, 16); lB += __shfl_xor(lB, 32);
  const float iA = 1.0f / lA, iB = 1.0f / lB;
#pragma unroll
  for (int nd = 0; nd < 4; ++nd) {
    float4 wv;
    wv.x = oA[nd][0] * iA; wv.y = oA[nd][1] * iA;
    wv.z = oA[nd][2] * iA; wv.w = oA[nd][3] * iA;
    *(float4*)(Ob + (size_t)(q0A + ln) * Dd + nd * 16 + quad * 4) = wv;
    wv.x = oB[nd][0] * iB; wv.y = oB[nd][1] * iB;
    wv.z = oB[nd][2] * iB; wv.w = oB[nd][3] * iB;
    *(float4*)(Ob + (size_t)(q0B + ln) * Dd + nd * 16 + quad * 4) = wv;
  }
}

}  // namespace

extern "C" void kernel_launch(void* const* d_in, const int* in_sizes, int n_in,
                              void* d_out, int out_size, void* d_ws, size_t ws_size,
                              hipStream_t stream) {
  const float* Q   = (const float*)d_in[0];
  const float* K   = (const float*)d_in[1];
  const float* V   = (const float*)d_in[2];
  const int*  mask = (const int*)d_in[3];
  float* Out = (float*)d_out;

  preprocess4<<<dim3(32, 32, 2), 256, 0, stream>>>(K, V, mask, (uint8_t*)d_ws);
  attn_fused14<<<dim3(Bb * Hh, Ss / 128), 256, 0, stream>>>(Q, (const uint8_t*)d_ws, Out);
  (void)ws_size; (void)in_sizes; (void)n_in; (void)out_size;
}

// Round 12
// 135.899 us; speedup vs baseline: 1.4258x; 1.3048x over previous
//
#include <hip/hip_runtime.h>
#include <hip/hip_bf16.h>
#include <stdint.h>

namespace {

constexpr int Bb = 2;
constexpr int Hh = 16;
constexpr int Ss = 2048;
constexpr int Dd = 64;
constexpr int KT = 64;                   // keys per stored tile
constexpr int NT = Ss / KT;              // 32 stored key tiles
constexpr int TILE_BYTES = KT * Dd * 2;  // 8192 B per bf16 tile
constexpr int BH_BYTES = NT * TILE_BYTES;
constexpr size_t KPRE_BYTES = (size_t)Bb * Hh * Ss * Dd * 2;  // 8 MB
constexpr size_t VPRE_OFF = KPRE_BYTES;
constexpr size_t MASK_OFF = 2 * KPRE_BYTES;

typedef __bf16 bf16x8 __attribute__((ext_vector_type(8)));
typedef float floatx4 __attribute__((ext_vector_type(4)));

// ---------------- preprocess4: ZERO LDS (validated R4) ----------------
__global__ __launch_bounds__(256) void preprocess4(
    const float* __restrict__ K, const float* __restrict__ V,
    const int* __restrict__ mask, uint8_t* __restrict__ ws)
{
  const int tid = threadIdx.x;
  const int kt = blockIdx.x;
  const int bh = blockIdx.y;

  if (blockIdx.z == 0) {
    const int c = tid & 7;
#pragma unroll
    for (int half = 0; half < 2; ++half) {
      const int row = (tid >> 3) + half * 32;
      const float4* src = (const float4*)(K + ((size_t)bh * 2048 + kt * 64 + row) * 64 + c * 8);
      const float4 a = src[0], b2 = src[1];
      bf16x8 pk;
      pk[0] = (__bf16)a.x;  pk[1] = (__bf16)a.y;  pk[2] = (__bf16)a.z;  pk[3] = (__bf16)a.w;
      pk[4] = (__bf16)b2.x; pk[5] = (__bf16)b2.y; pk[6] = (__bf16)b2.z; pk[7] = (__bf16)b2.w;
      uint8_t* dst = ws + (size_t)bh * BH_BYTES + kt * TILE_BYTES + row * 128 + ((c ^ (row & 7)) << 4);
      *(bf16x8*)dst = pk;
    }
    if (bh == 0 && kt < 16) {
      const int i = kt * 256 + tid;
      const int bb = i >> 11, key = i & 2047;
      const unsigned long long bal = __ballot(mask[bb * 2048 + key] != 0);
      if ((key & 63) == 0)
        ((unsigned long long*)(ws + MASK_OFF))[bb * NT + (key >> 6)] = bal;
    }
    return;
  }

  // ---- V: direct transposed gather (no LDS) ----
  const int d2  = tid & 31;
  const int c16 = tid >> 5;
  const int s2 = c16 & 1, q = c16 >> 1;
  const int k0 = 32 * s2 + 4 * q;
  const float* vbase = V + ((size_t)bh * 2048 + kt * 64) * 64;
  float2 col[8];
#pragma unroll
  for (int j = 0; j < 4; ++j) {
    col[j]     = *(const float2*)(vbase + (size_t)(k0 + j) * 64 + 2 * d2);
    col[4 + j] = *(const float2*)(vbase + (size_t)(k0 + 16 + j) * 64 + 2 * d2);
  }
#pragma unroll
  for (int h = 0; h < 2; ++h) {
    const int d = 2 * d2 + h;
    bf16x8 pv;
#pragma unroll
    for (int j = 0; j < 4; ++j) {
      pv[j]     = (__bf16)(h ? col[j].y     : col[j].x);
      pv[4 + j] = (__bf16)(h ? col[4 + j].y : col[4 + j].x);
    }
    uint8_t* dst = ws + VPRE_OFF + (size_t)bh * BH_BYTES + kt * TILE_BYTES + d * 128 + ((c16 ^ (d & 7)) << 4);
    *(bf16x8*)dst = pv;
  }
}

// -10000 * log2(e): reference's masked_fill value, in exp2 domain.
#define NEGM (-14426.950408889634f)
#define MFMA16 __builtin_amdgcn_mfma_f32_16x16x32_bf16

// ---------------- fused attention, T14 SCALARIZED staging ----------------
// R10/R11 failure mode identified: float4 STAGING ARRAYS passed as decayed
// pointers into loadRegs/writeLds lambdas land in SCRATCH (WRITE_SIZE 167-
// 199 MB, rule #20 via pointer-passing) - NOT a register-budget spill
// (R11: VGPR=84 with a 256 cap). Fix: eight NAMED float4 scalars moved via
// text-substitution macros - every access is a named SSA value, no arrays,
// no pointers. Geometry = R5 (KVBLK=64, 32 KiB LDS); barrier discipline:
// loads(it+2)->regs issued early, ds_write(it+1) right after the barrier,
// compute(it). Barrier drains lgkm only; global latency rides under a full
// iteration (~600 cyc) of compute. m214 T14 precedent: +17%.
__global__ __launch_bounds__(256, 2) void attn_fused15(
    const float* __restrict__ Q, const uint8_t* __restrict__ ws,
    float* __restrict__ Out)
{
  const int tid  = threadIdx.x;
  const int wave = tid >> 6;
  const int lane = tid & 63;
  const int ln   = lane & 15;
  const int quad = lane >> 4;

  const int bh   = blockIdx.x;  // 0..31
  const int qblk = blockIdx.y;  // 0..15
  const int b    = bh >> 4;

  const float* Qb = Q + (size_t)bh * Ss * Dd;
  float*       Ob = Out + (size_t)bh * Ss * Dd;
  const uint8_t* Kpre = ws + (size_t)bh * BH_BYTES;
  const uint8_t* Vpre = ws + VPRE_OFF + (size_t)bh * BH_BYTES;
  const unsigned long long* Mbits = (const unsigned long long*)(ws + MASK_OFF) + b * NT;

  __shared__ __align__(16) __bf16 Klds[2][64 * Dd];   // 2 x 8 KB
  __shared__ __align__(16) __bf16 Vlds[2][64 * Dd];   // 2 x 8 KB

  const int q0A = qblk * 128 + wave * 32;
  const int q0B = q0A + 16;

  // Q B-frags, pre-scaled by 1/8*log2(e). B[k=quad*8+j][n=ln] = Qs[q][d].
  const float QS = 0.125f * 1.44269504088896340736f;
  bf16x8 aqA0, aqA1, aqB0, aqB1;
  {
    const float* qpA = Qb + (size_t)(q0A + ln) * Dd + quad * 8;
    const float* qpB = Qb + (size_t)(q0B + ln) * Dd + quad * 8;
#pragma unroll
    for (int j = 0; j < 8; ++j) {
      aqA0[j] = (__bf16)(qpA[j] * QS);
      aqA1[j] = (__bf16)(qpA[32 + j] * QS);
      aqB0[j] = (__bf16)(qpB[j] * QS);
      aqB1[j] = (__bf16)(qpB[32 + j] * QS);
    }
  }

  floatx4 oA[4], oB[4];    // O^T C-layout: d = nd*16+quad*4+r, q = ln
  floatx4 laccA = (floatx4){0.f, 0.f, 0.f, 0.f};
  floatx4 laccB = (floatx4){0.f, 0.f, 0.f, 0.f};
#pragma unroll
  for (int nd = 0; nd < 4; ++nd) {
    oA[nd] = (floatx4){0.f, 0.f, 0.f, 0.f};
    oB[nd] = (floatx4){0.f, 0.f, 0.f, 0.f};
  }

  const int swz0 = (quad ^ (ln & 7)) << 4;
  const int swz1 = ((quad + 4) ^ (ln & 7)) << 4;
  const int soff = wave * 1024 + lane * 16;  // 4 KB per round, 2 rounds/tile

  // ---- staging state: NAMED scalars only (no arrays, no pointers) ----
  float4 kA0, kA1, vA0, vA1, kB0, kB1, vB0, vB1;

#define LOADREGS(IT, K0, K1, V0, V1)                                          \
  {                                                                           \
    const uint8_t* kp_ = Kpre + (size_t)(IT) * TILE_BYTES + soff;             \
    const uint8_t* vp_ = Vpre + (size_t)(IT) * TILE_BYTES + soff;             \
    K0 = *(const float4*)(kp_);                                               \
    K1 = *(const float4*)(kp_ + 4096);                                        \
    V0 = *(const float4*)(vp_);                                               \
    V1 = *(const float4*)(vp_ + 4096);                                        \
  }

#define WRITELDS(BUF, K0, K1, V0, V1)                                         \
  {                                                                           \
    *(float4*)((uint8_t*)Klds[(BUF)] + soff)        = K0;                     \
    *(float4*)((uint8_t*)Klds[(BUF)] + soff + 4096) = K1;                     \
    *(float4*)((uint8_t*)Vlds[(BUF)] + soff)        = V0;                     \
    *(float4*)((uint8_t*)Vlds[(BUF)] + soff + 4096) = V1;                     \
  }

// compute on buffer CUR with mask word MB (R5 body, unchanged)
#define COMPUTE(CUR, MB)                                                      \
  {                                                                           \
    const unsigned long long mb = (MB);                                       \
    const uint8_t* Kb = (const uint8_t*)Klds[(CUR)];                          \
    const uint8_t* Vb = (const uint8_t*)Vlds[(CUR)];                          \
    auto loadK = [&](int sub, bf16x8& b0, bf16x8& b1) {                       \
      const uint8_t* krow = Kb + (sub * 16 + ln) * 128;                       \
      b0 = *(const bf16x8*)(krow + swz0);                                     \
      b1 = *(const bf16x8*)(krow + swz1);                                     \
    };                                                                        \
    auto loadV = [&](int s2_, bf16x8* w) {                                    \
      _Pragma("unroll")                                                       \
      for (int nd = 0; nd < 4; ++nd) {                                        \
        const uint8_t* vrow = Vb + (nd * 16 + ln) * 128;                      \
        w[nd] = *(const bf16x8*)(vrow + (((quad * 2 + s2_) ^ (ln & 7)) << 4));\
      }                                                                       \
    };                                                                        \
    __builtin_amdgcn_s_setprio(1);                                            \
    bf16x8 kf0[2][2], kf1[2][2];                                              \
    bf16x8 vf[2][4];                                                          \
    loadK(0, kf0[0][0], kf1[0][0]);                                           \
    loadK(1, kf0[0][1], kf1[0][1]);                                           \
    loadV(0, vf[0]);                                                          \
    _Pragma("unroll")                                                         \
    for (int p = 0; p < 2; ++p) {                                             \
      if (p == 0) {                                                           \
        loadK(2, kf0[1][0], kf1[1][0]);                                       \
        loadK(3, kf0[1][1], kf1[1][1]);                                       \
        loadV(1, vf[1]);                                                      \
      }                                                                       \
      const uint32_t bits0 = (uint32_t)(mb >> ((2 * p) * 16 + quad * 4));     \
      const uint32_t bits1 = (uint32_t)(mb >> ((2 * p + 1) * 16 + quad * 4)); \
      floatx4 sA0, sA1, sB0, sB1;                                             \
      _Pragma("unroll")                                                       \
      for (int r = 0; r < 4; ++r) {                                           \
        const float b0v = ((bits0 >> r) & 1) ? NEGM : 0.f;                    \
        const float b1v = ((bits1 >> r) & 1) ? NEGM : 0.f;                    \
        sA0[r] = b0v; sB0[r] = b0v;                                           \
        sA1[r] = b1v; sB1[r] = b1v;                                           \
      }                                                                       \
      sA0 = MFMA16(kf0[p][0], aqA0, sA0, 0, 0, 0);                            \
      sA0 = MFMA16(kf1[p][0], aqA1, sA0, 0, 0, 0);                            \
      sB0 = MFMA16(kf0[p][0], aqB0, sB0, 0, 0, 0);                            \
      sB0 = MFMA16(kf1[p][0], aqB1, sB0, 0, 0, 0);                            \
      sA1 = MFMA16(kf0[p][1], aqA0, sA1, 0, 0, 0);                            \
      sA1 = MFMA16(kf1[p][1], aqA1, sA1, 0, 0, 0);                            \
      sB1 = MFMA16(kf0[p][1], aqB0, sB1, 0, 0, 0);                            \
      sB1 = MFMA16(kf1[p][1], aqB1, sB1, 0, 0, 0);                            \
      bf16x8 bpA, bpB;                                                        \
      _Pragma("unroll")                                                       \
      for (int r = 0; r < 4; ++r) {                                           \
        const float pA0 = __builtin_amdgcn_exp2f(sA0[r]);                     \
        const float pA1 = __builtin_amdgcn_exp2f(sA1[r]);                     \
        const float pB0 = __builtin_amdgcn_exp2f(sB0[r]);                     \
        const float pB1 = __builtin_amdgcn_exp2f(sB1[r]);                     \
        laccA[r] += pA0 + pA1;                                                \
        laccB[r] += pB0 + pB1;                                                \
        bpA[r] = (__bf16)pA0; bpA[4 + r] = (__bf16)pA1;                       \
        bpB[r] = (__bf16)pB0; bpB[4 + r] = (__bf16)pB1;                       \
      }                                                                       \
      _Pragma("unroll")                                                       \
      for (int nd = 0; nd < 4; ++nd) {                                        \
        oA[nd] = MFMA16(vf[p][nd], bpA, oA[nd], 0, 0, 0);                     \
        oB[nd] = MFMA16(vf[p][nd], bpB, oB[nd], 0, 0, 0);                     \
      }                                                                       \
    }                                                                         \
    __builtin_amdgcn_s_setprio(0);                                            \
  }

// ITER: barrier; ds_write tile IT+1 (W names); issue loads tile IT+2 (L
// names); compute tile IT. Barrier closes prev reads of buf[(IT+1)&1] and
// publishes prev ds_writes of buf[IT&1]; only lgkm drains (no vmcnt tail).
#define ITER(IT, WK0, WK1, WV0, WV1, LK0, LK1, LV0, LV1)                      \
  {                                                                           \
    __syncthreads();                                                          \
    if ((IT) + 1 < NT) WRITELDS(((IT) + 1) & 1, WK0, WK1, WV0, WV1);          \
    if ((IT) + 2 < NT) LOADREGS((IT) + 2, LK0, LK1, LV0, LV1);                \
    COMPUTE((IT) & 1, Mbits[(IT)]);                                           \
  }

  // prologue: tile0 -> B-names -> buf0; tile1 -> A-names (in flight).
  LOADREGS(0, kB0, kB1, vB0, vB1);
  WRITELDS(0, kB0, kB1, vB0, vB1);
  LOADREGS(1, kA0, kA1, vA0, vA1);

  for (int it2 = 0; it2 < NT; it2 += 2) {
    ITER(it2,     kA0, kA1, vA0, vA1, kB0, kB1, vB0, vB1);
    ITER(it2 + 1, kB0, kB1, vB0, vB1, kA0, kA1, vA0, vA1);
  }

#undef ITER
#undef COMPUTE
#undef WRITELDS
#undef LOADREGS

  // ---- epilogue: reduce l across quads, normalize, store ----
  float lA = (laccA[0] + laccA[1]) + (laccA[2] + laccA[3]);
  float lB = (laccB[0] + laccB[1]) + (laccB[2] + laccB[3]);
  lA += __shfl_xor(lA, 16); lA += __shfl_xor(lA, 32);
  lB += __shfl_xor(lB, 16); lB += __shfl_xor(lB, 32);
  const float iA = 1.0f / lA, iB = 1.0f / lB;
#pragma unroll
  for (int nd = 0; nd < 4; ++nd) {
    float4 wv;
    wv.x = oA[nd][0] * iA; wv.y = oA[nd][1] * iA;
    wv.z = oA[nd][2] * iA; wv.w = oA[nd][3] * iA;
    *(float4*)(Ob + (size_t)(q0A + ln) * Dd + nd * 16 + quad * 4) = wv;
    wv.x = oB[nd][0] * iB; wv.y = oB[nd][1] * iB;
    wv.z = oB[nd][2] * iB; wv.w = oB[nd][3] * iB;
    *(float4*)(Ob + (size_t)(q0B + ln) * Dd + nd * 16 + quad * 4) = wv;
  }
}

}  // namespace

extern "C" void kernel_launch(void* const* d_in, const int* in_sizes, int n_in,
                              void* d_out, int out_size, void* d_ws, size_t ws_size,
                              hipStream_t stream) {
  const float* Q   = (const float*)d_in[0];
  const float* K   = (const float*)d_in[1];
  const float* V   = (const float*)d_in[2];
  const int*  mask = (const int*)d_in[3];
  float* Out = (float*)d_out;

  preprocess4<<<dim3(32, 32, 2), 256, 0, stream>>>(K, V, mask, (uint8_t*)d_ws);
  attn_fused15<<<dim3(Bb * Hh, Ss / 128), 256, 0, stream>>>(Q, (const uint8_t*)d_ws, Out);
  (void)ws_size; (void)in_sizes; (void)n_in; (void)out_size;
}